// Round 13
// baseline (95.142 us; speedup 1.0000x reference)
//
#include <hip/hip_runtime.h>
#include <math.h>

#define BB 16
#define PP 4096
#define TT 1024
#define NC 12               // 12x12 cells of width 5.5 (> RADIUS 5: 3x3 coverage exact)
#define NCELL (NC * NC)     // 144
#define NBUK (NCELL * 4)    // 576 buckets = cell x class per batch
#define PCAP 32             // slots per bucket (lambda ~7.6; P(overflow) ~ 1e-12)
#define CSCALE 0.181818187f // 1/5.5
#define LIMKEY 0x41C80FFFu  // key <= this <=> quantized d2 <= 25.0f

// Phase 0 (16 blocks x 256, one per batch): fixed-capacity bucket scatter.
// LDS counters zeroed in-block and stored wholesale -> no global memset.
// No scan, no sort, 2 barriers (R12 lesson: scan/sort build cost >> its value).
__global__ __launch_bounds__(256) void build_kernel(const float* __restrict__ pred,
                                                    float* __restrict__ bx,
                                                    float* __restrict__ by,
                                                    unsigned* __restrict__ bpo,
                                                    unsigned* __restrict__ pcnt) {
    __shared__ unsigned cnt[NBUK];
    const int tid = threadIdx.x;
    const int b   = blockIdx.x;
    for (int i = tid; i < NBUK; i += 256) cnt[i] = 0;
    __syncthreads();

    const float4* src = (const float4*)(pred + (size_t)b * PP * 3);
    #pragma unroll
    for (int r = 0; r < 4; ++r) {
        const int f0 = r * 768 + 3 * tid;          // 4 triples = 3 float4s
        const float4 v0 = src[f0 + 0];
        const float4 v1 = src[f0 + 1];
        const float4 v2 = src[f0 + 2];
        const float pc[4] = {v0.x, v0.w, v1.z, v2.y};
        const float px[4] = {v0.y, v1.x, v1.w, v2.z};
        const float py[4] = {v0.z, v1.y, v2.x, v2.w};
        #pragma unroll
        for (int k = 0; k < 4; ++k) {
            const unsigned cx = (unsigned)(px[k] * CSCALE);   // x<64 -> cx<=11
            const unsigned cy = (unsigned)(py[k] * CSCALE);
            const unsigned buk = (cx * NC + cy) * 4 + (unsigned)pc[k];
            const unsigned slot = atomicAdd(&cnt[buk], 1u);
            if (slot < PCAP) {
                const size_t g = ((size_t)b * NBUK + buk) * PCAP + slot;
                bx[g]  = px[k];
                by[g]  = py[k];
                bpo[g] = (unsigned)(r * 1024 + tid * 4 + k);  // orig p in batch
            }
        }
    }
    __syncthreads();
    for (int i = tid; i < NBUK; i += 256)
        pcnt[b * NBUK + i] = min(cnt[i], (unsigned)PCAP);
}

// Phase 1 (64 blocks x 256): one thread per target (original order). Compute
// cell on the fly; scan the 3x3 neighborhood of its (cell, class) buckets
// (~68 preds avg). Packed key (d2_bits & ~0xFFF) | orig_p -> argmin +
// lowest-p tie-break via u32 min. part fully written -> no init.
__global__ __launch_bounds__(256) void match_kernel(const float* __restrict__ gt,
                                                    const float* __restrict__ bx,
                                                    const float* __restrict__ by,
                                                    const unsigned* __restrict__ bpo,
                                                    const unsigned* __restrict__ pcnt,
                                                    unsigned* __restrict__ part) {
    const int i = blockIdx.x * 256 + threadIdx.x;   // b*TT + t
    const int b = i >> 10;

    const float* g = gt + (size_t)i * 3;
    const float c = g[0], x = g[1], y = g[2];
    const unsigned cx = (unsigned)(x * CSCALE);
    const unsigned cy = (unsigned)(y * CSCALE);
    const unsigned cls = (unsigned)c;

    const int xs = cx ? -1 : 0, xe = (cx < NC - 1) ? 1 : 0;
    const int ys = cy ? -1 : 0, ye = (cy < NC - 1) ? 1 : 0;
    const unsigned* pcb = pcnt + b * NBUK;

    unsigned best = 0xFFFFFFFFu;
    for (int dx = xs; dx <= xe; ++dx) {
        for (int dy = ys; dy <= ye; ++dy) {
            const unsigned buk = (((unsigned)((int)cx + dx)) * NC
                                  + (unsigned)((int)cy + dy)) * 4 + cls;
            const unsigned n = pcb[buk];
            const size_t base = ((size_t)b * NBUK + buk) * PCAP;
            for (unsigned s = 0; s < n; ++s) {
                const float ddx = bx[base + s] - x;
                const float ddy = by[base + s] - y;
                const float d2 = fmaf(ddx, ddx, ddy * ddy);
                const unsigned kk = (__float_as_uint(d2) & 0xFFFFF000u) | bpo[base + s];
                best = min(best, kk);
            }
        }
    }
    part[i] = best;
}

// Phase 2: single block 1024 thr: radius-filter keys, bitmap distinct hit
// preds (8 KB LDS), popcount -> tp, F1 scalar.
__global__ __launch_bounds__(1024) void tail_kernel(const unsigned* __restrict__ part,
                                                    float* __restrict__ out) {
    __shared__ unsigned bm[BB * PP / 32];   // 2048 words
    for (int i = threadIdx.x; i < BB * PP / 32; i += 1024) bm[i] = 0;
    __syncthreads();

    #pragma unroll 4
    for (int i = threadIdx.x; i < BB * TT; i += 1024) {
        const unsigned k = part[i];
        if (k <= LIMKEY) {
            const unsigned g = (unsigned)(i >> 10) * PP + (k & 0xFFFu);
            atomicOr(&bm[g >> 5], 1u << (g & 31));
        }
    }
    __syncthreads();

    int sum = 0;
    for (int i = threadIdx.x; i < BB * PP / 32; i += 1024) sum += __popc(bm[i]);
    for (int off = 32; off; off >>= 1) sum += __shfl_down(sum, off, 64);

    __shared__ int ss[16];
    const int wid  = threadIdx.x >> 6;
    const int lane = threadIdx.x & 63;
    if (lane == 0) ss[wid] = sum;
    __syncthreads();
    if (threadIdx.x == 0) {
        int tp_i = 0;
        for (int w = 0; w < 16; ++w) tp_i += ss[w];
        const float tp = (float)tp_i;
        const float eps = 1e-6f;
        const float fp = (float)(BB * PP) - tp;
        const float fn = (float)(BB * TT) - tp;
        const float precision = (tp + eps) / (tp + eps + fp + eps);
        const float recall    = (tp + eps) / (tp + fn + eps);
        const float f1 = 2.0f * precision * recall / (precision + recall);
        out[0] = 1.0f - f1;
    }
}

extern "C" void kernel_launch(void* const* d_in, const int* in_sizes, int n_in,
                              void* d_out, int out_size, void* d_ws, size_t ws_size,
                              hipStream_t stream) {
    const float* pred = (const float*)d_in[0];  // (B, P, 3): cls, x, y
    const float* gt   = (const float*)d_in[1];  // (B, T, 3)
    float* out = (float*)d_out;

    char* ws = (char*)d_ws;
    const size_t BK = (size_t)BB * NBUK * PCAP; // 294912 slots
    float*    bx   = (float*)   (ws + 0);                  // 1.18 MB
    float*    by   = (float*)   (ws + BK * 4);             // 1.18 MB
    unsigned* bpo  = (unsigned*)(ws + BK * 8);             // 1.18 MB
    unsigned* pcnt = (unsigned*)(ws + BK * 12);            // 36 KB
    unsigned* part = (unsigned*)(ws + BK * 12 + 36864);    // 64 KB

    build_kernel<<<BB, 256, 0, stream>>>(pred, bx, by, bpo, pcnt);
    match_kernel<<<64, 256, 0, stream>>>(gt, bx, by, bpo, pcnt, part);
    tail_kernel<<<1, 1024, 0, stream>>>(part, out);
}

// Round 14
// 76.928 us; speedup vs baseline: 1.2368x; 1.2368x over previous
//
#include <hip/hip_runtime.h>
#include <math.h>

#define BB 16
#define PP 4096
#define TT 1024
#define NQ 4                // P-quarters (private buckets per (b,q) -> no cross-block sync)
#define NC 12               // 12x12 cells of width 5.5 (> RADIUS 5 + margin: 3x3 coverage exact)
#define NCELL (NC * NC)     // 144
#define NBUK (NCELL * 4)    // 576 buckets = cell x class
#define PCAP 16             // slots/bucket/quarter (lambda 1.78; P(overflow) ~1e-13)
#define CSCALE 0.181818187f // 1/5.5
#define LIMKEY 0x41C80FFFu  // key <= this <=> quantized d2 <= 25.0f

// Phase 0 (64 blocks x 1024 = whole machine): block = (batch, quarter), one pred
// per thread. LDS slot counters; one float4 slot per pred: (x, y, p_bits, -).
// Counters stored wholesale -> no global memset anywhere.
__global__ __launch_bounds__(1024) void build_kernel(const float* __restrict__ pred,
                                                     float4* __restrict__ buk,
                                                     unsigned* __restrict__ pcnt) {
    __shared__ unsigned cnt[NBUK];
    const int b   = blockIdx.x >> 2;
    const int q   = blockIdx.x & 3;
    const int tid = threadIdx.x;
    if (tid < NBUK) cnt[tid] = 0;
    __syncthreads();

    const int p = q * 1024 + tid;
    const float* pp = pred + ((size_t)b * PP + p) * 3;
    const float c = pp[0], x = pp[1], y = pp[2];
    const unsigned cx = (unsigned)(x * CSCALE);   // x < 64 -> cx <= 11
    const unsigned cy = (unsigned)(y * CSCALE);
    const unsigned id = (cx * NC + cy) * 4 + (unsigned)c;
    const unsigned slot = atomicAdd(&cnt[id], 1u);
    if (slot < PCAP) {
        float4 v;
        v.x = x; v.y = y;
        v.z = __uint_as_float((unsigned)p);   // bit-preserving store (no arithmetic)
        v.w = 0.0f;
        buk[(((size_t)blockIdx.x) * NBUK + id) * PCAP + slot] = v;
    }
    __syncthreads();
    if (tid < NBUK) pcnt[blockIdx.x * NBUK + tid] = min(cnt[tid], (unsigned)PCAP);
}

// Phase 1 (256 blocks x 256 = 65536 threads): thread = (quarter, target).
// Scan the 3x3 neighborhood of the target's (cell, class) in ITS quarter's
// buckets (~16 preds avg, one dwordx4 gather each). Packed key
// (d2_bits & ~0xFFF) | p -> argmin + lowest-p tie-break via u32 min.
// part[q][b*TT+t] fully written -> no init. No fences (R9 lesson).
__global__ __launch_bounds__(256) void match_kernel(const float* __restrict__ gt,
                                                    const float4* __restrict__ buk,
                                                    const unsigned* __restrict__ pcnt,
                                                    unsigned* __restrict__ part) {
    const int g = blockIdx.x * 256 + threadIdx.x;   // [0, 65536)
    const int q = g >> 14;
    const int i = g & 16383;                        // b*TT + t
    const int b = i >> 10;

    const float* gp = gt + (size_t)i * 3;
    const float c = gp[0], x = gp[1], y = gp[2];
    const unsigned cx  = (unsigned)(x * CSCALE);
    const unsigned cy  = (unsigned)(y * CSCALE);
    const unsigned cls = (unsigned)c;

    const int xs = cx ? -1 : 0, xe = (cx < NC - 1) ? 1 : 0;
    const int ys = cy ? -1 : 0, ye = (cy < NC - 1) ? 1 : 0;
    const int bq = b * NQ + q;
    const unsigned* pcb = pcnt + bq * NBUK;
    const float4* bukb = buk + (size_t)bq * NBUK * PCAP;

    unsigned best = 0xFFFFFFFFu;
    for (int dx = xs; dx <= xe; ++dx) {
        for (int dy = ys; dy <= ye; ++dy) {
            const unsigned id = (((unsigned)((int)cx + dx)) * NC
                                 + (unsigned)((int)cy + dy)) * 4 + cls;
            const unsigned n = pcb[id];
            const float4* s = bukb + id * PCAP;
            for (unsigned k = 0; k < n; ++k) {
                const float4 v = s[k];
                const float ddx = v.x - x;
                const float ddy = v.y - y;
                const float d2 = fmaf(ddx, ddx, ddy * ddy);
                const unsigned kk = (__float_as_uint(d2) & 0xFFFFF000u)
                                    | __float_as_uint(v.z);
                best = min(best, kk);
            }
        }
    }
    part[(size_t)q * (BB * TT) + i] = best;
}

// Phase 2: single block 1024 thr: min-combine the 4 quarters per target,
// radius-filter, bitmap distinct hit preds (8 KB LDS), popcount -> tp, F1.
__global__ __launch_bounds__(1024) void tail_kernel(const unsigned* __restrict__ part,
                                                    float* __restrict__ out) {
    __shared__ unsigned bm[BB * PP / 32];   // 2048 words
    for (int i = threadIdx.x; i < BB * PP / 32; i += 1024) bm[i] = 0;
    __syncthreads();

    #pragma unroll 4
    for (int i = threadIdx.x; i < BB * TT; i += 1024) {
        const unsigned k = min(min(part[i],               part[BB * TT + i]),
                               min(part[2 * BB * TT + i], part[3 * BB * TT + i]));
        if (k <= LIMKEY) {
            const unsigned g = (unsigned)(i >> 10) * PP + (k & 0xFFFu);
            atomicOr(&bm[g >> 5], 1u << (g & 31));
        }
    }
    __syncthreads();

    int sum = 0;
    for (int i = threadIdx.x; i < BB * PP / 32; i += 1024) sum += __popc(bm[i]);
    for (int off = 32; off; off >>= 1) sum += __shfl_down(sum, off, 64);

    __shared__ int ss[16];
    const int wid  = threadIdx.x >> 6;
    const int lane = threadIdx.x & 63;
    if (lane == 0) ss[wid] = sum;
    __syncthreads();
    if (threadIdx.x == 0) {
        int tp_i = 0;
        for (int w = 0; w < 16; ++w) tp_i += ss[w];
        const float tp = (float)tp_i;
        const float eps = 1e-6f;
        const float fp = (float)(BB * PP) - tp;
        const float fn = (float)(BB * TT) - tp;
        const float precision = (tp + eps) / (tp + eps + fp + eps);
        const float recall    = (tp + eps) / (tp + fn + eps);
        const float f1 = 2.0f * precision * recall / (precision + recall);
        out[0] = 1.0f - f1;
    }
}

extern "C" void kernel_launch(void* const* d_in, const int* in_sizes, int n_in,
                              void* d_out, int out_size, void* d_ws, size_t ws_size,
                              hipStream_t stream) {
    const float* pred = (const float*)d_in[0];  // (B, P, 3): cls, x, y
    const float* gt   = (const float*)d_in[1];  // (B, T, 3)
    float* out = (float*)d_out;

    char* ws = (char*)d_ws;
    float4*   buk  = (float4*)  (ws + 0);          // 64*576*16*16 B = 9.44 MB
    unsigned* pcnt = (unsigned*)(ws + 9437184);    // 64*576*4 = 147 KB
    unsigned* part = (unsigned*)(ws + 9584640);    // 4*16384*4 = 256 KB

    build_kernel<<<BB * NQ, 1024, 0, stream>>>(pred, buk, pcnt);
    match_kernel<<<256, 256, 0, stream>>>(gt, buk, pcnt, part);
    tail_kernel<<<1, 1024, 0, stream>>>(part, out);
}

// Round 15
// 70.363 us; speedup vs baseline: 1.3522x; 1.0933x over previous
//
#include <hip/hip_runtime.h>
#include <math.h>

#define BB 16
#define PP 4096
#define TT 1024
#define JT 16
#define QTR 1024           // preds per block (P split in 4 quarters)
#define LIMKEY 0x41C80FFFu // key <= this  <=>  quantized d2 <= 25.0f (0x41C80000)

// Empirical best (R8: 71.1 us). Grid: 1024 blocks = 16 b x 16 target-tiles x
// 4 P-quarters. Block = 256 thr = 4 waves; wave owns 16 targets scanning its
// 1024-pred quarter (lane = p mod 64). Class-island encoding:
// x' = fma(cls, 128, x) -> cross-class d2 >= 4096, auto-rejected by the
// deferred radius test (d2 <= 25); no per-pair class compare. Packed key
// (d2_bits & ~0xFFF) | p gives argmin + lowest-p tie-break via one v_min_u32.
// Inner loop = 6 VALU/pair. part[qtr][b*TT+t] fully written -> no ws init.
// No fences (R9: device-fence storm = +85 us). No LDS staging / SoA transpose /
// spatial hash: all tested neutral-or-worse (R5/R11/R12-14) - the residual is
// harness fill (40 us @ 83% HBM peak) + launch/latency floor.
__global__ __launch_bounds__(256) void match_kernel(const float* __restrict__ pred,
                                                    const float* __restrict__ gt,
                                                    unsigned* __restrict__ part) {
    const int blk   = blockIdx.x;
    const int b     = blk >> 6;           // 64 blocks per batch
    const int ttile = (blk >> 2) & 15;    // 64 targets per block
    const int qtr   = blk & 3;
    const int wave  = threadIdx.x >> 6;   // 0..3
    const int lane  = threadIdx.x & 63;
    const int tbase = ttile * 64 + wave * JT;
    const int pbase = qtr * QTR;

    const float* gb = gt + ((size_t)(b * TT + tbase)) * 3;
    float gx[JT], gy[JT];
    unsigned key[JT];
    #pragma unroll
    for (int j = 0; j < JT; ++j) {
        const float c = gb[j * 3 + 0];
        gx[j] = fmaf(c, 128.0f, gb[j * 3 + 1]);   // island offset by class
        gy[j] = gb[j * 3 + 2];
        key[j] = 0xFFFFFFFFu;
    }

    const float* pl = pred + (size_t)b * PP * 3 + (size_t)(pbase + lane) * 3;

    #pragma unroll 4
    for (int i = 0; i < QTR / 64; ++i) {
        const float pc = pl[0];
        const float px = pl[1];
        const float py = pl[2];
        pl += 192;
        const float pxp = fmaf(pc, 128.0f, px);
        const unsigned po = (unsigned)(pbase + (i << 6) + lane);
        #pragma unroll
        for (int j = 0; j < JT; ++j) {
            const float dx = pxp - gx[j];
            const float dy = py - gy[j];
            const float d2 = fmaf(dx, dx, dy * dy);
            const unsigned kk = (__float_as_uint(d2) & 0xFFFFF000u) | po;
            key[j] = min(key[j], kk);
        }
    }

    for (int off = 32; off; off >>= 1) {
        #pragma unroll
        for (int j = 0; j < JT; ++j) {
            const unsigned o = __shfl_down(key[j], off, 64);
            key[j] = min(key[j], o);
        }
    }

    if (lane == 0) {
        #pragma unroll
        for (int j = 0; j < JT; ++j)
            part[(size_t)qtr * (BB * TT) + b * TT + tbase + j] = key[j];
    }
}

// 16 blocks (one per batch): min-combine 4 quarters per target, radius-filter,
// bitmap distinct hit preds in 512B LDS, popcount -> psum[b].
__global__ __launch_bounds__(256) void count_kernel(const unsigned* __restrict__ part,
                                                    int* __restrict__ psum) {
    __shared__ unsigned bm[PP / 32];   // 128 words
    if (threadIdx.x < 128) bm[threadIdx.x] = 0;
    __syncthreads();

    const int b = blockIdx.x;
    const unsigned* pb = part + b * TT;
    for (int i = threadIdx.x; i < TT; i += 256) {
        unsigned k = min(min(pb[i], pb[BB * TT + i]),
                         min(pb[2 * BB * TT + i], pb[3 * BB * TT + i]));
        if (k <= LIMKEY) {
            const unsigned p = k & 0xFFFu;
            atomicOr(&bm[p >> 5], 1u << (p & 31));
        }
    }
    __syncthreads();

    int sum = (threadIdx.x < 128) ? (int)__popc(bm[threadIdx.x]) : 0;
    for (int off = 32; off; off >>= 1) sum += __shfl_down(sum, off, 64);
    __shared__ int ss[4];
    if ((threadIdx.x & 63) == 0) ss[threadIdx.x >> 6] = sum;
    __syncthreads();
    if (threadIdx.x == 0) psum[b] = ss[0] + ss[1] + ss[2] + ss[3];
}

// One wave: sum the 16 partials, F1 scalar.
__global__ void f1_kernel(const int* __restrict__ psum, float* __restrict__ out) {
    int v = (threadIdx.x < BB) ? psum[threadIdx.x] : 0;
    for (int off = 32; off; off >>= 1) v += __shfl_down(v, off, 64);
    if (threadIdx.x == 0) {
        const float tp = (float)v;
        const float eps = 1e-6f;
        const float fp = (float)(BB * PP) - tp;
        const float fn = (float)(BB * TT) - tp;
        const float precision = (tp + eps) / (tp + eps + fp + eps);
        const float recall    = (tp + eps) / (tp + fn + eps);
        const float f1 = 2.0f * precision * recall / (precision + recall);
        out[0] = 1.0f - f1;
    }
}

extern "C" void kernel_launch(void* const* d_in, const int* in_sizes, int n_in,
                              void* d_out, int out_size, void* d_ws, size_t ws_size,
                              hipStream_t stream) {
    const float* pred = (const float*)d_in[0];  // (B, P, 3): cls, x, y
    const float* gt   = (const float*)d_in[1];  // (B, T, 3)
    float* out = (float*)d_out;

    unsigned* part = (unsigned*)d_ws;                     // 4 * B*T u32 = 256 KB
    int* psum = (int*)((char*)d_ws + 4 * BB * TT * 4);    // 16 ints, always written

    match_kernel<<<BB * 16 * 4, 256, 0, stream>>>(pred, gt, part);
    count_kernel<<<BB, 256, 0, stream>>>(part, psum);
    f1_kernel<<<1, 64, 0, stream>>>(psum, out);
}